// Round 4
// baseline (2111.025 us; speedup 1.0000x reference)
//
#include <hip/hip_runtime.h>

// NeuralODE: B=1024, D=64, F=8, H=256, 196 substeps x 6 dopri5 stages.
// R4: the R2/R3 AGPR pathology decoded: launch_bounds' 2nd arg is a MINIMUM
// waves/EU; the compiler targeted 4-5 waves/EU (VGPR_Count 128 = 512/4, 88 =
// 512/5) and parked the pinned weights in AGPRs -> v_accvgpr_read per use
// (~710 VALU instr/thread/stage vs ~330 useful). amdgpu_waves_per_eu(2,2)
// pins the target -> 256-VGPR arch budget -> weights stay addressable.
// With the budget real, use the high-intensity partitions:
//   phase1: thread owns W1 cols (c0, c0+128) for ONE row rw=tid>>7
//           [144 VGPR], z-reads 18 b128 (was 36)
//   phase2: thread (g=tid>>5, d0=tid&31) owns W2[g*32..+31][d0, d0+32]
//           [64 VGPR], both rows, h-reads 16 b128 (was 32)
// Waves 0,1 carry ODE state rows 0,1. All hot LDS reads are 1-2 address
// broadcasts (free); red[] stride-9 (coprime 32 -> 2-way, free).

__device__ __forceinline__ float fast_tanh(float x) {
    float e = __expf(2.0f * x);
    return 1.0f - 2.0f / (e + 1.0f);   // saturates correctly, ~1e-6 abs err
}

__global__ __attribute__((amdgpu_waves_per_eu(2, 2))) __launch_bounds__(256)
void node_kernel(const float* __restrict__ x0,
                 const float* __restrict__ t_eval,
                 const float* __restrict__ t_u,
                 const float* __restrict__ u_batch,
                 const float* __restrict__ W1,
                 const float* __restrict__ b1,
                 const float* __restrict__ W2,
                 const float* __restrict__ b2,
                 float* __restrict__ out)
{
    __shared__ __align__(16) float zsh[2][72];     // [row][D+F]
    __shared__ __align__(16) float hsh[2][256];    // [row][hidden]
    __shared__ __align__(16) float red[2][64][9];  // [row][d][chunk], stride 9
    __shared__ __align__(16) float ush[6][2][8];   // interp u per stage/row

    const int tid = threadIdx.x;
    const int w   = tid >> 6;           // wave id; state row if <2
    const int l   = tid & 63;           // lane; state dim
    const int rw  = tid >> 7;           // phase1 row
    const int c0  = tid & 127;          // phase1 cols c0, c0+128
    const int g   = tid >> 5;           // phase2 j-chunk 0..7
    const int d0  = tid & 31;           // phase2 cols d0, d0+32
    const int blk = blockIdx.x;

    // --- weights into VGPRs (coalesced) ---
    float w1a[72], w1b[72];
#pragma unroll
    for (int i = 0; i < 72; ++i) {
        w1a[i] = W1[i * 256 + c0];
        w1b[i] = W1[i * 256 + c0 + 128];
    }
    float w2a[32], w2b[32];
#pragma unroll
    for (int j = 0; j < 32; ++j) {
        w2a[j] = W2[(g * 32 + j) * 64 + d0];
        w2b[j] = W2[(g * 32 + j) * 64 + d0 + 32];
    }
    // pin: asm outputs can't be rematerialized -> one-time load
#pragma unroll
    for (int i = 0; i < 72; ++i) { asm("" : "+v"(w1a[i])); asm("" : "+v"(w1b[i])); }
#pragma unroll
    for (int j = 0; j < 32; ++j) { asm("" : "+v"(w2a[j])); asm("" : "+v"(w2b[j])); }

    const float b1a = b1[c0];
    const float b1b = b1[c0 + 128];
    const float b2d = b2[l];

    // ODE state: wave 0 -> row 0, wave 1 -> row 1 (lane l holds dim l)
    float x = 0.f;
    if (w < 2) {
        x = x0[(blk * 2 + w) * 64 + l];
        out[(blk * 2 + w) * 3200 + l] = x;     // t_eval[0]
    }
    float k1 = 0.f, k2 = 0.f, k3 = 0.f, k4 = 0.f, k5 = 0.f, k6 = 0.f;

#pragma unroll 1
    for (int step = 0; step < 196; ++step) {
        const int n = step >> 2;
        const int m = step & 3;
        const float te0 = t_eval[n];
        const float dtc = t_eval[n + 1] - te0;
        const float t   = te0 + dtc * (0.25f * (float)m);
        const float dt  = dtc * 0.25f;

        // --- prefetch+interp u for all 6 stages of this step ---
        if (tid < 96) {
            const int s  = tid >> 4;
            const int rr = (tid >> 3) & 1;
            const int f  = tid & 7;
            float tsv;
            switch (s) {
                case 0: tsv = t; break;
                case 1: tsv = t + dt * (1.0f/5.0f); break;
                case 2: tsv = t + dt * (3.0f/10.0f); break;
                case 3: tsv = t + dt * (4.0f/5.0f); break;
                case 4: tsv = t + dt * (8.0f/9.0f); break;
                default: tsv = t + dt; break;
            }
            int idx = (int)(tsv * 127.0f);      // == searchsorted-1 (gap >= 4e-5)
            idx = idx < 0 ? 0 : (idx > 126 ? 126 : idx);
            const float ta = t_u[idx];
            const float tb = t_u[idx + 1];
            const float wt = (tsv - ta) / (tb - ta);
            const int base = (blk * 2 + rr) * (128 * 8) + idx * 8 + f;
            const float u0v = u_batch[base];
            const float u1v = u_batch[base + 8];
            ush[s][rr][f] = fmaf(wt, u1v - u0v, u0v);
        }
        __syncthreads();

#pragma unroll 1
        for (int s = 0; s < 6; ++s) {
            // --- staging: waves 0,1 publish z = [x_s, u_s] for their row ---
            if (w < 2) {
                float xs;
                switch (s) {
                    case 0: xs = x; break;
                    case 1: xs = fmaf(dt, k1 * (1.0f/5.0f), x); break;
                    case 2: xs = fmaf(dt, fmaf(3.0f/40.0f, k1, (9.0f/40.0f)*k2), x); break;
                    case 3: xs = fmaf(dt, (44.0f/45.0f)*k1 + (-56.0f/15.0f)*k2 + (32.0f/9.0f)*k3, x); break;
                    case 4: xs = fmaf(dt, (19372.0f/6561.0f)*k1 + (-25360.0f/2187.0f)*k2
                                         + (64448.0f/6561.0f)*k3 + (-212.0f/729.0f)*k4, x); break;
                    default: xs = fmaf(dt, (9017.0f/3168.0f)*k1 + (-355.0f/33.0f)*k2
                                          + (46732.0f/5247.0f)*k3 + (49.0f/176.0f)*k4
                                          + (-5103.0f/18656.0f)*k5, x); break;
                }
                zsh[w][l] = xs;
                if (l < 8) zsh[w][64 + l] = ush[s][w][l];
            }
            __syncthreads();

            // --- phase 1: h[rw][c0], h[rw][c0+128]; each z read feeds 8 FMAs ---
            float a0 = b1a, a1 = b1b;
#pragma unroll
            for (int i = 0; i < 72; i += 4) {
                const float4 z = *(const float4*)&zsh[rw][i];
                a0 = fmaf(z.x, w1a[i],   a0);  a1 = fmaf(z.x, w1b[i],   a1);
                a0 = fmaf(z.y, w1a[i+1], a0);  a1 = fmaf(z.y, w1b[i+1], a1);
                a0 = fmaf(z.z, w1a[i+2], a0);  a1 = fmaf(z.z, w1b[i+2], a1);
                a0 = fmaf(z.w, w1a[i+3], a0);  a1 = fmaf(z.w, w1b[i+3], a1);
            }
            hsh[rw][c0]       = fast_tanh(a0);
            hsh[rw][c0 + 128] = fast_tanh(a1);
            __syncthreads();

            // --- phase 2: (row 0/1) x (d0, d0+32) over 32-j chunk;
            //     each h read feeds 8 FMAs ---
            float p00 = 0.f, p01 = 0.f, p10 = 0.f, p11 = 0.f;
            const int jb = g * 32;
#pragma unroll
            for (int j = 0; j < 32; j += 4) {
                const float4 h0 = *(const float4*)&hsh[0][jb + j];
                const float4 h1 = *(const float4*)&hsh[1][jb + j];
                p00 = fmaf(h0.x, w2a[j],   p00);  p01 = fmaf(h0.x, w2b[j],   p01);
                p10 = fmaf(h1.x, w2a[j],   p10);  p11 = fmaf(h1.x, w2b[j],   p11);
                p00 = fmaf(h0.y, w2a[j+1], p00);  p01 = fmaf(h0.y, w2b[j+1], p01);
                p10 = fmaf(h1.y, w2a[j+1], p10);  p11 = fmaf(h1.y, w2b[j+1], p11);
                p00 = fmaf(h0.z, w2a[j+2], p00);  p01 = fmaf(h0.z, w2b[j+2], p01);
                p10 = fmaf(h1.z, w2a[j+2], p10);  p11 = fmaf(h1.z, w2b[j+2], p11);
                p00 = fmaf(h0.w, w2a[j+3], p00);  p01 = fmaf(h0.w, w2b[j+3], p01);
                p10 = fmaf(h1.w, w2a[j+3], p10);  p11 = fmaf(h1.w, w2b[j+3], p11);
            }
            red[0][d0][g]      = p00;
            red[0][d0 + 32][g] = p01;
            red[1][d0][g]      = p10;
            red[1][d0 + 32][g] = p11;
            __syncthreads();

            // --- reduce 8 chunks -> k (state waves only) ---
            if (w < 2) {
                const float* rp = red[w][l];
                const float kv = b2d + (((rp[0] + rp[1]) + (rp[2] + rp[3]))
                                      + ((rp[4] + rp[5]) + (rp[6] + rp[7])));
                switch (s) {
                    case 0: k1 = kv; break;
                    case 1: k2 = kv; break;
                    case 2: k3 = kv; break;
                    case 3: k4 = kv; break;
                    case 4: k5 = kv; break;
                    default: k6 = kv; break;
                }
            }
        }

        // --- dopri5 update ---
        if (w < 2) {
            x = fmaf(dt, (35.0f/384.0f)*k1 + (500.0f/1113.0f)*k3 + (125.0f/192.0f)*k4
                        + (-2187.0f/6784.0f)*k5 + (11.0f/84.0f)*k6, x);
            if (m == 3) out[(blk * 2 + w) * 3200 + (n + 1) * 64 + l] = x;
        }
    }
}

extern "C" void kernel_launch(void* const* d_in, const int* in_sizes, int n_in,
                              void* d_out, int out_size, void* d_ws, size_t ws_size,
                              hipStream_t stream) {
    const float* x0      = (const float*)d_in[0];
    const float* t_eval  = (const float*)d_in[1];
    const float* t_u     = (const float*)d_in[2];
    const float* u_batch = (const float*)d_in[3];
    const float* W1      = (const float*)d_in[4];
    const float* b1      = (const float*)d_in[5];
    const float* W2      = (const float*)d_in[6];
    const float* b2      = (const float*)d_in[7];
    float* out = (float*)d_out;

    node_kernel<<<dim3(512), dim3(256), 0, stream>>>(
        x0, t_eval, t_u, u_batch, W1, b1, W2, b2, out);
}